// Round 12
// baseline (182.245 us; speedup 1.0000x reference)
//
#include <hip/hip_runtime.h>
#include <hip/hip_bf16.h>

#define B_N 4096
#define M_N 16384
#define D_N 512
#define NC_N 100
#define NCP 112
#define BT 64
#define SPLITM 8
#define SC 0.36067376022224085f   // log2(e)/4 — folded into A,X at prep
#define SC2 (SC * SC)

typedef float f32x4 __attribute__((ext_vector_type(4)));
typedef short bf16x8 __attribute__((ext_vector_type(8)));

__device__ __forceinline__ unsigned short f2bf(float f) {
  unsigned int u = __float_as_uint(f);
  u += 0x7FFFu + ((u >> 16) & 1u);
  return (unsigned short)(u >> 16);
}

// Squared norms of 512-elem rows, scaled by SC2 (fold beta into distances).
__global__ void prep_norms(const float* __restrict__ src, float* __restrict__ norms) {
  int row = blockIdx.x * 4 + (threadIdx.x >> 6);
  int lane = threadIdx.x & 63;
  const float4* s = (const float4*)(src + (size_t)row * D_N);
  float4 v0 = s[lane * 2];
  float4 v1 = s[lane * 2 + 1];
  float acc = v0.x * v0.x + v0.y * v0.y + v0.z * v0.z + v0.w * v0.w +
              v1.x * v1.x + v1.y * v1.y + v1.z * v1.z + v1.w * v1.w;
  #pragma unroll
  for (int off = 1; off < 64; off <<= 1) acc += __shfl_xor(acc, off);
  if (lane == 0) norms[row] = acc * SC2;
}

// A fp32 -> A2 bf16 (scaled by SC) in MFMA-fragment order.
__global__ void prep_a2(const float* __restrict__ A, unsigned short* __restrict__ A2) {
  int idx = blockIdx.x * 256 + threadIdx.x;
  int r16 = idx & 15;
  int g = (idx >> 4) & 3;
  int half = (idx >> 6) & 1;
  int ki = (idx >> 7) & 15;
  int T = idx >> 11;
  int row = T * 32 + half * 16 + r16;
  int col = ki * 32 + g * 8;
  const float4* s = (const float4*)(A + (size_t)row * D_N + col);
  float4 v0 = s[0];
  float4 v1 = s[1];
  uint4 w4;
  w4.x = f2bf(v0.x * SC) | ((unsigned int)f2bf(v0.y * SC) << 16);
  w4.y = f2bf(v0.z * SC) | ((unsigned int)f2bf(v0.w * SC) << 16);
  w4.z = f2bf(v1.x * SC) | ((unsigned int)f2bf(v1.y * SC) << 16);
  w4.w = f2bf(v1.z * SC) | ((unsigned int)f2bf(v1.w * SC) << 16);
  *(uint4*)(A2 + (size_t)idx * 8) = w4;
}

// X fp32 -> X2 bf16 (scaled by SC) in per-64-row-tile fragment order.
__global__ void prep_x2(const float* __restrict__ X, unsigned short* __restrict__ X2) {
  int o = blockIdx.x * 256 + threadIdx.x;     // B_N*D_N/8 total
  int l = o & 63;
  int c = (o >> 6) & 63;
  int bx = o >> 12;
  int bs = c & 3;
  int ki = c >> 2;
  int r16 = l & 15;
  int g = l >> 4;
  int row = bx * 64 + bs * 16 + r16;
  int col = ki * 32 + g * 8;
  const float4* s = (const float4*)(X + (size_t)row * D_N + col);
  float4 v0 = s[0];
  float4 v1 = s[1];
  uint4 w4;
  w4.x = f2bf(v0.x * SC) | ((unsigned int)f2bf(v0.y * SC) << 16);
  w4.y = f2bf(v0.z * SC) | ((unsigned int)f2bf(v0.w * SC) << 16);
  w4.z = f2bf(v1.x * SC) | ((unsigned int)f2bf(v1.y * SC) << 16);
  w4.w = f2bf(v1.z * SC) | ((unsigned int)f2bf(v1.w * SC) << 16);
  *(uint4*)(X2 + (size_t)o * 8) = w4;
}

// C fp32 (M x 100) -> CT2 bf16, fragment order with mu-permuted k-slots:
// slot j holds C[T*32 + 4g + (j&3) + 16*(j>>2)][ct*16 + r16] (c>=100 -> 0).
__global__ void prep_ct2(const float* __restrict__ C, unsigned short* __restrict__ CT2) {
  int idx = blockIdx.x * 256 + threadIdx.x;
  int r16 = idx & 15;
  int g = (idx >> 4) & 3;
  int rest = idx >> 6;
  int ct = rest % 7;
  int T = rest / 7;
  int c = ct * 16 + r16;
  unsigned short e[8];
  #pragma unroll
  for (int j = 0; j < 8; ++j) {
    int m = T * 32 + 4 * g + (j & 3) + 16 * (j >> 2);
    e[j] = (c < NC_N) ? f2bf(C[(size_t)m * NC_N + c]) : (unsigned short)0;
  }
  uint4 w4;
  w4.x = e[0] | ((unsigned int)e[1] << 16);
  w4.y = e[2] | ((unsigned int)e[3] << 16);
  w4.z = e[4] | ((unsigned int)e[5] << 16);
  w4.w = e[6] | ((unsigned int)e[7] << 16);
  *(uint4*)(CT2 + (size_t)idx * 8) = w4;
}

// Main fused kernel: wave = 32m x 64b; P in registers (mu-permuted CT2);
// X tile in LDS fragment order (conflict-free). Wave-pairs on a SIMD are
// desynced by a one-time half-iteration s_sleep so one wave's epilogue
// (VALU/trans) overlaps the other's QK MFMAs.
__global__ __launch_bounds__(512, 2)
void fused_main(const unsigned short* __restrict__ A2,
                const unsigned short* __restrict__ X2,
                const unsigned short* __restrict__ CT2,
                const float* __restrict__ aa, const float* __restrict__ xx,
                float* __restrict__ pacc, float* __restrict__ pden, int splitm) {
  __shared__ union {
    unsigned short Xl[BT * 512];                   // 64 KB, fragment-ordered
    struct { float Cacc[NCP * BT]; float Cden[BT]; } fin;  // aliased after loop
  } sh;

  const int t = threadIdx.x;
  const int w = t >> 6;
  const int l = t & 63;
  const int g = l >> 4;
  const int r16 = l & 15;

  // XCD-aware bijective swizzle: same-XCD blocks share sidx -> share A2 chunk.
  const int bid = blockIdx.x;
  int sidx, bx;
  if (splitm == 8) {
    sidx = bid & 7;
    bx = bid >> 3;
  } else if (splitm == 4) {
    sidx = (bid & 7) >> 1;
    bx = ((bid >> 3) << 1) | (bid & 1);
  } else {
    sidx = bid / (B_N / BT);
    bx = bid % (B_N / BT);
  }
  const int bbase = bx * BT;

  // stage X tile: linear 64KB copy (coalesced global, conflict-free LDS)
  #pragma unroll
  for (int i = 0; i < 8; ++i) {
    int q = t + 512 * i;
    uint4 v = *(const uint4*)(X2 + ((size_t)bx * 4096 + q) * 8);
    *(uint4*)(&sh.Xl[q * 8]) = v;
  }
  __syncthreads();

  // desync the two waves sharing each SIMD (w and w+4) by ~half a T-iter
  if (w & 4) __builtin_amdgcn_s_sleep(20);

  float xxv[4];
  #pragma unroll
  for (int bs = 0; bs < 4; ++bs) xxv[bs] = xx[bbase + bs * 16 + r16];

  f32x4 oacc[7][4];
  #pragma unroll
  for (int ct = 0; ct < 7; ++ct)
    #pragma unroll
    for (int bs = 0; bs < 4; ++bs) oacc[ct][bs] = (f32x4){0.f, 0.f, 0.f, 0.f};
  float den[4] = {0.f, 0.f, 0.f, 0.f};

  const bf16x8* Ab = (const bf16x8*)A2;
  const bf16x8* Cb = (const bf16x8*)CT2;
  const bf16x8* Xf = (const bf16x8*)sh.Xl;

  for (int T = sidx + splitm * w; T < M_N / 32; T += splitm * 8) {
    const int m0 = T * 32;

    // ---- QK: S = (cA) . (cX) over d=512 ----
    f32x4 sacc[2][4];
    #pragma unroll
    for (int ms = 0; ms < 2; ++ms)
      #pragma unroll
      for (int bs = 0; bs < 4; ++bs) sacc[ms][bs] = (f32x4){0.f, 0.f, 0.f, 0.f};

    #pragma unroll 4
    for (int ki = 0; ki < 16; ++ki) {
      bf16x8 a0 = Ab[(size_t)((T * 16 + ki) * 2 + 0) * 64 + l];
      bf16x8 a1 = Ab[(size_t)((T * 16 + ki) * 2 + 1) * 64 + l];
      #pragma unroll
      for (int bs = 0; bs < 4; ++bs) {
        bf16x8 xf = Xf[(ki * 4 + bs) * 64 + l];    // lane-linear, 0 conflicts
        sacc[0][bs] = __builtin_amdgcn_mfma_f32_16x16x32_bf16(a0, xf, sacc[0][bs], 0, 0, 0);
        sacc[1][bs] = __builtin_amdgcn_mfma_f32_16x16x32_bf16(a1, xf, sacc[1][bs], 0, 0, 0);
      }
    }

    // ---- epilogue + PV: d2 pre-scaled, e = exp2(-sqrt(d2)); P in regs ----
    bf16x8 cf[7];
    #pragma unroll
    for (int ct = 0; ct < 7; ++ct)
      cf[ct] = Cb[(size_t)(T * 7 + ct) * 64 + l];
    f32x4 aaL = *(const f32x4*)(aa + m0 + 4 * g);
    f32x4 aaH = *(const f32x4*)(aa + m0 + 16 + 4 * g);

    #pragma unroll
    for (int bs = 0; bs < 4; ++bs) {
      unsigned wz[2][2];
      #pragma unroll
      for (int ms = 0; ms < 2; ++ms) {
        f32x4 s4 = sacc[ms][bs];
        f32x4 aam = ms ? aaH : aaL;
        float e[4];
        #pragma unroll
        for (int r = 0; r < 4; ++r) {
          float d2 = aam[r] + xxv[bs] - 2.0f * s4[r];
          float dist = __builtin_amdgcn_sqrtf(fmaxf(d2, 0.0f));
          e[r] = exp2f(-dist);                      // scale folded into data
        }
        den[bs] += (e[0] + e[1]) + (e[2] + e[3]);
        __hip_bfloat162 h01 = __float22bfloat162_rn(make_float2(e[0], e[1]));
        __hip_bfloat162 h23 = __float22bfloat162_rn(make_float2(e[2], e[3]));
        wz[ms][0] = *reinterpret_cast<unsigned*>(&h01);
        wz[ms][1] = *reinterpret_cast<unsigned*>(&h23);
      }
      union { uint4 u; bf16x8 v; } pf;
      pf.u = make_uint4(wz[0][0], wz[0][1], wz[1][0], wz[1][1]);
      #pragma unroll
      for (int ct = 0; ct < 7; ++ct)
        oacc[ct][bs] = __builtin_amdgcn_mfma_f32_16x16x32_bf16(cf[ct], pf.v, oacc[ct][bs], 0, 0, 0);
    }
  }

  // reduce den across the 4 lane-groups (column sums)
  #pragma unroll
  for (int bs = 0; bs < 4; ++bs) {
    float d = den[bs];
    d += __shfl_xor(d, 16);
    d += __shfl_xor(d, 32);
    den[bs] = d;
  }

  // combine the 8 waves' partials in LDS (Cacc aliases Xl — Xl dead now)
  __syncthreads();
  for (int i = t; i < NCP * BT; i += 512) sh.fin.Cacc[i] = 0.f;
  if (t < BT) sh.fin.Cden[t] = 0.f;
  __syncthreads();

  for (int ww = 0; ww < 8; ++ww) {
    if (w == ww) {
      #pragma unroll
      for (int ct = 0; ct < 7; ++ct)
        #pragma unroll
        for (int bs = 0; bs < 4; ++bs)
          #pragma unroll
          for (int r = 0; r < 4; ++r)
            sh.fin.Cacc[(ct * 16 + 4 * g + r) * BT + bs * 16 + r16] += oacc[ct][bs][r];
      if (g == 0)
        #pragma unroll
        for (int bs = 0; bs < 4; ++bs) sh.fin.Cden[bs * 16 + r16] += den[bs];
    }
    __syncthreads();
  }

  // write partial accumulators: pacc[s][c][b], pden[s][b]
  float* paccS = pacc + (size_t)sidx * NCP * B_N;
  for (int i = t; i < NCP * BT; i += 512) {
    int c = i >> 6, bl = i & (BT - 1);
    paccS[(size_t)c * B_N + bbase + bl] = sh.fin.Cacc[i];
  }
  if (t < BT) pden[sidx * B_N + bbase + t] = sh.fin.Cden[t];
}

// Finalize: 256 blocks, each owns 16 b's; tile (16c x 16b) threads.
#define FB 16
__global__ __launch_bounds__(256)
void finalize(const float* __restrict__ pacc, const float* __restrict__ pden,
              float* __restrict__ out, int splitm) {
  __shared__ float tile[NC_N][FB];
  __shared__ float dinv[FB];
  const int t = threadIdx.x;
  const int b0 = blockIdx.x * FB;
  const int tb = t & 15;
  const int tc = t >> 4;

  if (t < FB) {
    float dn = 0.f;
    for (int s = 0; s < splitm; ++s) dn += pden[s * B_N + b0 + t];
    dinv[t] = 1.0f / dn;
  }

  for (int c = tc; c < NC_N; c += 16) {
    float a = 0.f;
    for (int s = 0; s < splitm; ++s)
      a += pacc[((size_t)s * NCP + c) * B_N + b0 + tb];
    tile[c][tb] = a;
  }
  __syncthreads();

  for (int i = t; i < FB * NC_N; i += 256) {
    int b = i / NC_N, c = i - b * NC_N;
    out[(size_t)(b0 + b) * NC_N + c] = tile[c][b] * dinv[b];
  }
}

extern "C" void kernel_launch(void* const* d_in, const int* in_sizes, int n_in,
                              void* d_out, int out_size, void* d_ws, size_t ws_size,
                              hipStream_t stream) {
  const float* X = (const float*)d_in[0];
  const float* A = (const float*)d_in[1];
  const float* C = (const float*)d_in[2];
  float* out = (float*)d_out;

  char* ws = (char*)d_ws;
  size_t off = 0;
  auto alloc = [&](size_t bytes) -> void* {
    void* p = ws + off;
    off += (bytes + 255) & ~(size_t)255;
    return p;
  };
  unsigned short* A2  = (unsigned short*)alloc((size_t)M_N * D_N * 2);
  unsigned short* X2  = (unsigned short*)alloc((size_t)B_N * D_N * 2);
  unsigned short* CT2 = (unsigned short*)alloc((size_t)NCP * M_N * 2);
  float* aa = (float*)alloc((size_t)M_N * 4);
  float* xx = (float*)alloc((size_t)B_N * 4);

  size_t per_split = ((size_t)NCP * B_N * 4 + 256) + ((size_t)B_N * 4 + 256);
  int splitm = SPLITM;
  while (splitm > 1 && off + (size_t)splitm * per_split > ws_size) splitm >>= 1;
  float* pacc = (float*)alloc((size_t)splitm * NCP * B_N * 4);
  float* pden = (float*)alloc((size_t)splitm * B_N * 4);

  prep_norms<<<B_N / 4, 256, 0, stream>>>(X, xx);
  prep_norms<<<M_N / 4, 256, 0, stream>>>(A, aa);
  prep_a2<<<(M_N * D_N / 8) / 256, 256, 0, stream>>>(A, A2);
  prep_x2<<<(B_N * D_N / 8) / 256, 256, 0, stream>>>(X, X2);
  prep_ct2<<<(512 * 7 * 64) / 256, 256, 0, stream>>>(C, CT2);
  fused_main<<<(B_N / BT) * splitm, 512, 0, stream>>>(A2, X2, CT2, aa, xx, pacc, pden, splitm);
  finalize<<<B_N / FB, 256, 0, stream>>>(pacc, pden, out, splitm);
}

// Round 13
// 170.930 us; speedup vs baseline: 1.0662x; 1.0662x over previous
//
#include <hip/hip_runtime.h>
#include <hip/hip_bf16.h>

#define B_N 4096
#define M_N 16384
#define D_N 512
#define NC_N 100
#define NCP 112
#define BT 32
#define SPLITM 4
#define SC 0.36067376022224085f   // log2(e)/4 — folded into A,X at prep
#define SC2 (SC * SC)

typedef float f32x4 __attribute__((ext_vector_type(4)));
typedef short bf16x8 __attribute__((ext_vector_type(8)));

__device__ __forceinline__ unsigned short f2bf(float f) {
  unsigned int u = __float_as_uint(f);
  u += 0x7FFFu + ((u >> 16) & 1u);
  return (unsigned short)(u >> 16);
}

// Squared norms of 512-elem rows, scaled by SC2 (fold beta into distances).
__global__ void prep_norms(const float* __restrict__ src, float* __restrict__ norms) {
  int row = blockIdx.x * 4 + (threadIdx.x >> 6);
  int lane = threadIdx.x & 63;
  const float4* s = (const float4*)(src + (size_t)row * D_N);
  float4 v0 = s[lane * 2];
  float4 v1 = s[lane * 2 + 1];
  float acc = v0.x * v0.x + v0.y * v0.y + v0.z * v0.z + v0.w * v0.w +
              v1.x * v1.x + v1.y * v1.y + v1.z * v1.z + v1.w * v1.w;
  #pragma unroll
  for (int off = 1; off < 64; off <<= 1) acc += __shfl_xor(acc, off);
  if (lane == 0) norms[row] = acc * SC2;
}

// A fp32 -> A2 bf16 (scaled by SC) in MFMA-fragment order: chunk (T32, ki, half),
// lane l holds A[T*32 + half*16 + (l&15)][ki*32 + (l>>4)*8 ..+7].
__global__ void prep_a2(const float* __restrict__ A, unsigned short* __restrict__ A2) {
  int idx = blockIdx.x * 256 + threadIdx.x;
  int r16 = idx & 15;
  int g = (idx >> 4) & 3;
  int half = (idx >> 6) & 1;
  int ki = (idx >> 7) & 15;
  int T = idx >> 11;
  int row = T * 32 + half * 16 + r16;
  int col = ki * 32 + g * 8;
  const float4* s = (const float4*)(A + (size_t)row * D_N + col);
  float4 v0 = s[0];
  float4 v1 = s[1];
  uint4 w4;
  w4.x = f2bf(v0.x * SC) | ((unsigned int)f2bf(v0.y * SC) << 16);
  w4.y = f2bf(v0.z * SC) | ((unsigned int)f2bf(v0.w * SC) << 16);
  w4.z = f2bf(v1.x * SC) | ((unsigned int)f2bf(v1.y * SC) << 16);
  w4.w = f2bf(v1.z * SC) | ((unsigned int)f2bf(v1.w * SC) << 16);
  *(uint4*)(A2 + (size_t)idx * 8) = w4;
}

// X fp32 -> X2 bf16 (scaled by SC) in per-32-row-tile fragment order:
// uint4 index o: lane l=o&63, chunk c=(o>>6)&31 (c = ki*2+bs), tile bx=o>>11.
// lane l=(g*16+r16) holds X[bx*32 + bs*16 + r16][ki*32 + g*8 ..+7].
__global__ void prep_x2(const float* __restrict__ X, unsigned short* __restrict__ X2) {
  int o = blockIdx.x * 256 + threadIdx.x;     // B_N*D_N/8 total
  int l = o & 63;
  int c = (o >> 6) & 31;
  int bx = o >> 11;
  int bs = c & 1;
  int ki = c >> 1;
  int r16 = l & 15;
  int g = l >> 4;
  int row = bx * 32 + bs * 16 + r16;
  int col = ki * 32 + g * 8;
  const float4* s = (const float4*)(X + (size_t)row * D_N + col);
  float4 v0 = s[0];
  float4 v1 = s[1];
  uint4 w4;
  w4.x = f2bf(v0.x * SC) | ((unsigned int)f2bf(v0.y * SC) << 16);
  w4.y = f2bf(v0.z * SC) | ((unsigned int)f2bf(v0.w * SC) << 16);
  w4.z = f2bf(v1.x * SC) | ((unsigned int)f2bf(v1.y * SC) << 16);
  w4.w = f2bf(v1.z * SC) | ((unsigned int)f2bf(v1.w * SC) << 16);
  *(uint4*)(X2 + (size_t)o * 8) = w4;
}

// C fp32 (M x 100) -> CT2 bf16, fragment order with mu-permuted k-slots:
// slot j holds C[T*32 + 4g + (j&3) + 16*(j>>2)][ct*16 + r16] (c>=100 -> 0).
__global__ void prep_ct2(const float* __restrict__ C, unsigned short* __restrict__ CT2) {
  int idx = blockIdx.x * 256 + threadIdx.x;
  int r16 = idx & 15;
  int g = (idx >> 4) & 3;
  int rest = idx >> 6;
  int ct = rest % 7;
  int T = rest / 7;
  int c = ct * 16 + r16;
  unsigned short e[8];
  #pragma unroll
  for (int j = 0; j < 8; ++j) {
    int m = T * 32 + 4 * g + (j & 3) + 16 * (j >> 2);
    e[j] = (c < NC_N) ? f2bf(C[(size_t)m * NC_N + c]) : (unsigned short)0;
  }
  uint4 w4;
  w4.x = e[0] | ((unsigned int)e[1] << 16);
  w4.y = e[2] | ((unsigned int)e[3] << 16);
  w4.z = e[4] | ((unsigned int)e[5] << 16);
  w4.w = e[6] | ((unsigned int)e[7] << 16);
  *(uint4*)(CT2 + (size_t)idx * 8) = w4;
}

// Main fused kernel: wave = 32m x 32b (acc regs 72 -> 4 waves/SIMD, 2 blk/CU);
// P in registers (mu-permuted CT2); X tile fragment-ordered (conflict-free).
__global__ __launch_bounds__(512, 4)
void fused_main(const unsigned short* __restrict__ A2,
                const unsigned short* __restrict__ X2,
                const unsigned short* __restrict__ CT2,
                const float* __restrict__ aa, const float* __restrict__ xx,
                float* __restrict__ pacc, float* __restrict__ pden, int splitm) {
  __shared__ union {
    unsigned short Xl[BT * 512];                   // 32 KB, fragment-ordered
    struct { float Cacc[NCP * BT]; float Cden[BT]; } fin;  // aliased after loop
  } sh;

  const int t = threadIdx.x;
  const int w = t >> 6;
  const int l = t & 63;
  const int g = l >> 4;
  const int r16 = l & 15;

  // XCD-aware bijective swizzle: same-XCD blocks share sidx -> share A2 chunk.
  const int bid = blockIdx.x;
  int sidx, bx;
  if (splitm == 4) {
    sidx = (bid & 7) >> 1;                 // XCD pair under round-robin dispatch
    bx = ((bid >> 3) << 1) | (bid & 1);    // bijective onto 0..127
  } else if (splitm == 2) {
    sidx = (bid & 7) >> 2;
    bx = ((bid >> 3) << 2) | (bid & 3);
  } else {
    sidx = 0;
    bx = bid;
  }
  const int bbase = bx * BT;

  // stage X tile: linear 32KB copy (coalesced global, conflict-free LDS)
  #pragma unroll
  for (int i = 0; i < 4; ++i) {
    int q = t + 512 * i;
    uint4 v = *(const uint4*)(X2 + ((size_t)bx * 2048 + q) * 8);
    *(uint4*)(&sh.Xl[q * 8]) = v;
  }
  __syncthreads();

  float xxv[2];
  #pragma unroll
  for (int bs = 0; bs < 2; ++bs) xxv[bs] = xx[bbase + bs * 16 + r16];

  f32x4 oacc[7][2];
  #pragma unroll
  for (int ct = 0; ct < 7; ++ct)
    #pragma unroll
    for (int bs = 0; bs < 2; ++bs) oacc[ct][bs] = (f32x4){0.f, 0.f, 0.f, 0.f};
  float den[2] = {0.f, 0.f};

  const bf16x8* Ab = (const bf16x8*)A2;
  const bf16x8* Cb = (const bf16x8*)CT2;
  const bf16x8* Xf = (const bf16x8*)sh.Xl;

  for (int T = sidx + splitm * w; T < M_N / 32; T += splitm * 8) {
    const int m0 = T * 32;

    // ---- QK: S = (cA) . (cX) over d=512 ----
    f32x4 sacc[2][2];
    #pragma unroll
    for (int ms = 0; ms < 2; ++ms)
      #pragma unroll
      for (int bs = 0; bs < 2; ++bs) sacc[ms][bs] = (f32x4){0.f, 0.f, 0.f, 0.f};

    #pragma unroll 4
    for (int ki = 0; ki < 16; ++ki) {
      bf16x8 a0 = Ab[(size_t)((T * 16 + ki) * 2 + 0) * 64 + l];
      bf16x8 a1 = Ab[(size_t)((T * 16 + ki) * 2 + 1) * 64 + l];
      #pragma unroll
      for (int bs = 0; bs < 2; ++bs) {
        bf16x8 xf = Xf[(ki * 2 + bs) * 64 + l];    // lane-linear, 0 conflicts
        sacc[0][bs] = __builtin_amdgcn_mfma_f32_16x16x32_bf16(a0, xf, sacc[0][bs], 0, 0, 0);
        sacc[1][bs] = __builtin_amdgcn_mfma_f32_16x16x32_bf16(a1, xf, sacc[1][bs], 0, 0, 0);
      }
    }

    // ---- epilogue + PV: e = exp2(-sqrt(d2)); P stays in registers ----
    f32x4 aaL = *(const f32x4*)(aa + m0 + 4 * g);
    f32x4 aaH = *(const f32x4*)(aa + m0 + 16 + 4 * g);

    #pragma unroll
    for (int bs = 0; bs < 2; ++bs) {
      unsigned wz[2][2];
      #pragma unroll
      for (int ms = 0; ms < 2; ++ms) {
        f32x4 s4 = sacc[ms][bs];
        f32x4 aam = ms ? aaH : aaL;
        float e[4];
        #pragma unroll
        for (int r = 0; r < 4; ++r) {
          float d2 = aam[r] + xxv[bs] - 2.0f * s4[r];
          float dist = __builtin_amdgcn_sqrtf(fmaxf(d2, 0.0f));
          e[r] = exp2f(-dist);                      // scale folded into data
        }
        den[bs] += (e[0] + e[1]) + (e[2] + e[3]);
        __hip_bfloat162 h01 = __float22bfloat162_rn(make_float2(e[0], e[1]));
        __hip_bfloat162 h23 = __float22bfloat162_rn(make_float2(e[2], e[3]));
        wz[ms][0] = *reinterpret_cast<unsigned*>(&h01);
        wz[ms][1] = *reinterpret_cast<unsigned*>(&h23);
      }
      union { uint4 u; bf16x8 v; } pf;
      pf.u = make_uint4(wz[0][0], wz[0][1], wz[1][0], wz[1][1]);
      #pragma unroll
      for (int ct = 0; ct < 7; ++ct) {
        bf16x8 cf = Cb[(size_t)(T * 7 + ct) * 64 + l];
        oacc[ct][bs] = __builtin_amdgcn_mfma_f32_16x16x32_bf16(cf, pf.v, oacc[ct][bs], 0, 0, 0);
      }
    }
  }

  // reduce den across the 4 lane-groups (column sums)
  #pragma unroll
  for (int bs = 0; bs < 2; ++bs) {
    float d = den[bs];
    d += __shfl_xor(d, 16);
    d += __shfl_xor(d, 32);
    den[bs] = d;
  }

  // combine the 8 waves' partials in LDS (Cacc aliases Xl — Xl dead now)
  __syncthreads();
  for (int i = t; i < NCP * BT; i += 512) sh.fin.Cacc[i] = 0.f;
  if (t < BT) sh.fin.Cden[t] = 0.f;
  __syncthreads();

  for (int ww = 0; ww < 8; ++ww) {
    if (w == ww) {
      #pragma unroll
      for (int ct = 0; ct < 7; ++ct)
        #pragma unroll
        for (int bs = 0; bs < 2; ++bs)
          #pragma unroll
          for (int r = 0; r < 4; ++r)
            sh.fin.Cacc[(ct * 16 + 4 * g + r) * BT + bs * 16 + r16] += oacc[ct][bs][r];
      if (g == 0)
        #pragma unroll
        for (int bs = 0; bs < 2; ++bs) sh.fin.Cden[bs * 16 + r16] += den[bs];
    }
    __syncthreads();
  }

  // write partial accumulators: pacc[s][c][b], pden[s][b]
  float* paccS = pacc + (size_t)sidx * NCP * B_N;
  for (int i = t; i < NCP * BT; i += 512) {
    int c = i / BT, bl = i & (BT - 1);
    paccS[(size_t)c * B_N + bbase + bl] = sh.fin.Cacc[i];
  }
  if (t < BT) pden[sidx * B_N + bbase + t] = sh.fin.Cden[t];
}

// Finalize: 256 blocks, each owns 16 b's; tile (16c x 16b) threads.
#define FB 16
__global__ __launch_bounds__(256)
void finalize(const float* __restrict__ pacc, const float* __restrict__ pden,
              float* __restrict__ out, int splitm) {
  __shared__ float tile[NC_N][FB];
  __shared__ float dinv[FB];
  const int t = threadIdx.x;
  const int b0 = blockIdx.x * FB;
  const int tb = t & 15;
  const int tc = t >> 4;

  if (t < FB) {
    float dn = 0.f;
    for (int s = 0; s < splitm; ++s) dn += pden[s * B_N + b0 + t];
    dinv[t] = 1.0f / dn;
  }

  for (int c = tc; c < NC_N; c += 16) {
    float a = 0.f;
    for (int s = 0; s < splitm; ++s)
      a += pacc[((size_t)s * NCP + c) * B_N + b0 + tb];
    tile[c][tb] = a;
  }
  __syncthreads();

  for (int i = t; i < FB * NC_N; i += 256) {
    int b = i / NC_N, c = i - b * NC_N;
    out[(size_t)(b0 + b) * NC_N + c] = tile[c][b] * dinv[b];
  }
}

extern "C" void kernel_launch(void* const* d_in, const int* in_sizes, int n_in,
                              void* d_out, int out_size, void* d_ws, size_t ws_size,
                              hipStream_t stream) {
  const float* X = (const float*)d_in[0];
  const float* A = (const float*)d_in[1];
  const float* C = (const float*)d_in[2];
  float* out = (float*)d_out;

  char* ws = (char*)d_ws;
  size_t off = 0;
  auto alloc = [&](size_t bytes) -> void* {
    void* p = ws + off;
    off += (bytes + 255) & ~(size_t)255;
    return p;
  };
  unsigned short* A2  = (unsigned short*)alloc((size_t)M_N * D_N * 2);
  unsigned short* X2  = (unsigned short*)alloc((size_t)B_N * D_N * 2);
  unsigned short* CT2 = (unsigned short*)alloc((size_t)NCP * M_N * 2);
  float* aa = (float*)alloc((size_t)M_N * 4);
  float* xx = (float*)alloc((size_t)B_N * 4);

  size_t per_split = ((size_t)NCP * B_N * 4 + 256) + ((size_t)B_N * 4 + 256);
  int splitm = SPLITM;
  while (splitm > 1 && off + (size_t)splitm * per_split > ws_size) splitm >>= 1;
  float* pacc = (float*)alloc((size_t)splitm * NCP * B_N * 4);
  float* pden = (float*)alloc((size_t)splitm * B_N * 4);

  prep_norms<<<B_N / 4, 256, 0, stream>>>(X, xx);
  prep_norms<<<M_N / 4, 256, 0, stream>>>(A, aa);
  prep_a2<<<(M_N * D_N / 8) / 256, 256, 0, stream>>>(A, A2);
  prep_x2<<<(B_N * D_N / 8) / 256, 256, 0, stream>>>(X, X2);
  prep_ct2<<<(512 * 7 * 64) / 256, 256, 0, stream>>>(C, CT2);
  fused_main<<<(B_N / BT) * splitm, 512, 0, stream>>>(A2, X2, CT2, aa, xx, pacc, pden, splitm);
  finalize<<<B_N / FB, 256, 0, stream>>>(pacc, pden, out, splitm);
}